// Round 11
// baseline (110.650 us; speedup 1.0000x reference)
//
#include <hip/hip_runtime.h>
#include <hip/hip_bf16.h>

#define DIN 64
#define DOUT 62
#define ICH 32
#define OCH 64

typedef __bf16 bf16x8 __attribute__((ext_vector_type(8)));
typedef float f32x4 __attribute__((ext_vector_type(4)));
typedef float f32x8 __attribute__((ext_vector_type(8)));
typedef float f32x16 __attribute__((ext_vector_type(16)));

#define AS1U(p) ((const __attribute__((address_space(1))) unsigned int*)(p))
#define AS3U(p) ((__attribute__((address_space(3))) unsigned int*)(p))

// ---------- prep: W -> Wre3 in 32x32x16-fragment-linear order ----------
// Wre3[(((tap*2+mt)*2+kh)*64+lane)*8+j] = bf16( W[oc=mt*32+(lane&31)][ic=kh*16+(lane>>5)*8+j][tap] )
// Per tap: 2*2*64 = 256 int4.  loadA(tap) = 4 coalesced dwordx4 (1KB segments).
__global__ void prep_w(const float* __restrict__ W, unsigned short* __restrict__ Wre3) {
    int idx = blockIdx.x * 256 + threadIdx.x;        // 27*2*2*64*8 = 55296
    if (idx >= 27 * OCH * ICH) return;
    int j    = idx & 7;
    int lane = (idx >> 3) & 63;
    int kh   = (idx >> 9) & 1;
    int mt   = (idx >> 10) & 1;
    int tap  = idx >> 11;
    int oc   = mt * 32 + (lane & 31);
    int ic   = kh * 16 + (lane >> 5) * 8 + j;
    float v  = W[((size_t)oc * ICH + ic) * 27 + tap];
    Wre3[idx] = __builtin_bit_cast(unsigned short, (__bf16)v);
}

// ---------- prep: x[b][ic][z][y][w] f32 -> xp[b][z][y][w][ic] bf16, slot-XOR baked in ----------
__global__ void prep_x(const float* __restrict__ x, unsigned short* __restrict__ xp) {
    int idx = blockIdx.x * 256 + threadIdx.x;        // 2*64*64*64 = 524288
    int w = idx & 63;
    int y = (idx >> 6) & 63;
    int z = (idx >> 12) & 63;
    int b = idx >> 18;
    const float* xb = x + ((size_t)b * ICH) * 262144 + (size_t)z * 4096 + y * 64 + w;
    int4* op = (int4*)(xp + (size_t)idx * 32);       // 64B per (b,z,y,w)
    const int m = (w >> 1) & 3;
#pragma unroll
    for (int s = 0; s < 4; ++s) {
        int icg = s ^ m;
        bf16x8 pk;
#pragma unroll
        for (int j = 0; j < 8; ++j)
            pk[j] = (__bf16)xb[(size_t)(icg * 8 + j) * 262144];
        op[s] = __builtin_bit_cast(int4, pk);
    }
}

// ---------- main: implicit GEMM, 32x32x16 MFMA, per-tap interleaved staging ----------
// block tile: (b, d, 4 h-rows) x 64 oc x 64 w.  wave = one h row; per wave 2x2 32x32 tiles.
// LDS plane 24KB: [y(6)][w(64)][4 slots x 16B], swizzle pre-baked in xp.
__global__ __launch_bounds__(256, 3) void conv3d_mfma_pk(
    const unsigned short* __restrict__ Wre3,
    const unsigned short* __restrict__ xp,
    float* __restrict__ out)
{
    __shared__ char xs[2 * 24576 + 256];             // 2 plane bufs + guard

    const int tid  = threadIdx.x;
    const int lane = tid & 63;
    const int wave = tid >> 6;

    // bijective XCD-aware swizzle (nwg = 1984 = 8*248 exactly)
    const int orig = blockIdx.x;
    const int lid  = (orig & 7) * 248 + (orig >> 3);
    const int ht = lid & 15;
    const int rr = lid >> 4;
    const int d  = rr % DOUT;
    const int b  = rr / DOUT;
    const int h0 = ht * 4;

    const int l31 = lane & 31;                       // w-in-tile / oc-in-tile
    const int lhi = lane >> 5;                       // k-subgroup (8 ic) within k-half
    const int row = wave;                            // h row

    // one 1KB chunk of a plane (c = wave*6+i), one global_load_lds_dwordx4
    auto stage_chunk = [&](char* buf, int z, int i) {
        int c  = wave * 6 + i;                       // 0..23
        int yl = c >> 2;                             // y row 0..5
        int srow = h0 + yl; if (srow > 63) srow = 63;   // clamped rows feed only discarded h
        const unsigned short* src =
            xp + (((size_t)(b * DIN + z) * DIN + srow) * DIN) * 32 + (c & 3) * 512 + lane * 8;
        __builtin_amdgcn_global_load_lds(AS1U(src), AS3U(buf + c * 1024), 16, 0, 0);
    };
    // A: af[q], q = mt*2+kh — 4 coalesced dwordx4 per tap (tap stride = 256 int4!)
    auto loadA = [&](int tap, int4* af) {
        const int4* wp = (const int4*)Wre3 + (size_t)tap * 256 + lane;   // 256 int4/tap
#pragma unroll
        for (int q = 0; q < 4; ++q)
            af[q] = wp[q * 64];
    };
    // B: dst[kh*2+nt] — 4 x ds_read_b128, conflict-free under the slot-XOR
    auto readB = [&](const char* buf, int ky, int kx, int4* dst) {
#pragma unroll
        for (int kh = 0; kh < 2; ++kh)
#pragma unroll
            for (int nt = 0; nt < 2; ++nt) {
                int wb = nt * 32 + l31 + kx;
                if (nt == 1 && wb > 63) wb = 63;     // cols 62/63 only (discarded outputs)
                int g  = kh * 2 + lhi;
                int sl = g ^ ((wb >> 1) & 3);
                dst[kh * 2 + nt] = *(const int4*)(buf + ((row + ky) * 64 + wb) * 64 + sl * 16);
            }
    };

    char* bufA = xs;
    char* bufB = xs + 24576;

#pragma unroll
    for (int i = 0; i < 6; ++i) stage_chunk(bufA, d, i);   // plane kz=0 (burst, once)
    int4 af[2][4];
    loadA(0, af[0]);

    f32x16 acc[2][2];
#pragma unroll
    for (int mt = 0; mt < 2; ++mt)
#pragma unroll
        for (int nt = 0; nt < 2; ++nt)
#pragma unroll
            for (int r = 0; r < 16; ++r) acc[mt][nt][r] = 0.f;

    __syncthreads();                                 // plane 0 ready

    int4 bfr[2][4];

#pragma unroll                                        // kz static -> all indices compile-time
    for (int kz = 0; kz < 3; ++kz) {
        char* cur = (kz & 1) ? bufB : bufA;
        char* nxt = (kz & 1) ? bufA : bufB;
        readB(cur, 0, 0, bfr[0]);                    // per-segment B prologue

#pragma unroll
        for (int t = 0; t < 9; ++t) {
            const int T = kz * 9 + t;
            if (T < 26) loadA(T + 1, af[(T + 1) & 1]);                        // A: 1-deep
            if (t < 8)  readB(cur, (t + 1) / 3, (t + 1) % 3, bfr[(t + 1) & 1]); // B: 1-deep
            if (kz < 2 && t < 6) stage_chunk(nxt, d + kz + 1, t);   // after loadA (vmcnt order)

            __builtin_amdgcn_s_setprio(1);
#pragma unroll
            for (int mt = 0; mt < 2; ++mt)
#pragma unroll
                for (int nt = 0; nt < 2; ++nt) {
                    acc[mt][nt] = __builtin_amdgcn_mfma_f32_32x32x16_bf16(
                        __builtin_bit_cast(bf16x8, af[T & 1][mt * 2 + 0]),
                        __builtin_bit_cast(bf16x8, bfr[t & 1][0 * 2 + nt]),
                        acc[mt][nt], 0, 0, 0);
                    acc[mt][nt] = __builtin_amdgcn_mfma_f32_32x32x16_bf16(
                        __builtin_bit_cast(bf16x8, af[T & 1][mt * 2 + 1]),
                        __builtin_bit_cast(bf16x8, bfr[t & 1][1 * 2 + nt]),
                        acc[mt][nt], 0, 0, 0);
                }
            __builtin_amdgcn_s_setprio(0);
        }
        if (kz < 2) __syncthreads();                 // next plane landed
    }

    // ---- store: D col=lane&31 -> w, row=(r&3)+8*(r>>2)+4*(lane>>5) -> oc ----
    const int h = h0 + row;
    if (h < DOUT) {
#pragma unroll
        for (int mt = 0; mt < 2; ++mt) {
#pragma unroll
            for (int r = 0; r < 16; ++r) {
                int oc = mt * 32 + (r & 3) + 8 * (r >> 2) + 4 * lhi;
                size_t ob = ((((size_t)b * OCH + oc) * DOUT + d) * DOUT + h) * DOUT;
#pragma unroll
                for (int nt = 0; nt < 2; ++nt) {
                    int ww = nt * 32 + l31;
                    if (ww < DOUT) out[ob + ww] = acc[mt][nt][r];
                }
            }
        }
    }
}

// ---------- fallback (ws too small): reg-staged 16x16 kernel, f32 W direct ----------
__global__ __launch_bounds__(256, 3) void conv3d_mfma_fb(
    const float* __restrict__ x, const float* __restrict__ W,
    float* __restrict__ out)
{
    __shared__ char xs[2][6 * 66 * 64];

    const int tid  = threadIdx.x;
    const int lane = tid & 63;
    const int wave = tid >> 6;

    const int orig = blockIdx.x;
    const int lid  = (orig & 7) * 248 + (orig >> 3);
    const int ht = lid & 15;
    const int rr = lid >> 4;
    const int d  = rr % DOUT;
    const int b  = rr / DOUT;
    const int h0 = ht * 4;

    const int wlo = lane & 15;
    const int whi = lane >> 4;
    const int row = wave;

    const int icg  = wave;
    const int w    = lane;
    const int slot = icg ^ ((w >> 1) & 3);

    auto issueRow = [&](int z, int y) -> f32x8 {
        int gy = h0 + y; if (gy > 63) gy = 63;
        const float* xp2 = x + (((size_t)(b * ICH + icg * 8) * DIN + z) * DIN + gy) * DIN + w;
        f32x8 s;
#pragma unroll
        for (int j = 0; j < 8; ++j) s[j] = xp2[(size_t)j * DIN * DIN * DIN];
        return s;
    };
    auto writeRow = [&](char* buf, int y, f32x8 s) {
        bf16x8 pk;
#pragma unroll
        for (int j = 0; j < 8; ++j) pk[j] = (__bf16)s[j];
        *(int4*)(buf + ((y * 66 + w) * 64 + slot * 16)) = __builtin_bit_cast(int4, pk);
    };
    auto loadA = [&](int tap, int4* af) {
#pragma unroll
        for (int mt = 0; mt < 4; ++mt) {
            const float* wp = W + ((size_t)(mt * 16 + wlo) * ICH + whi * 8) * 27 + tap;
            bf16x8 t;
#pragma unroll
            for (int j = 0; j < 8; ++j) t[j] = (__bf16)wp[j * 27];
            af[mt] = __builtin_bit_cast(int4, t);
        }
    };
    auto readB = [&](const char* buf, int ky, int kx, int4* dst) {
#pragma unroll
        for (int nt = 0; nt < 4; ++nt) {
            int wb = nt * 16 + wlo + kx;
            int sl = whi ^ ((wb >> 1) & 3);
            dst[nt] = *(const int4*)(buf + (((row + ky) * 66 + wb) * 64 + sl * 16));
        }
    };

    if (tid < 96) {
        int bu = tid / 48, q2 = tid % 48;
        int y = q2 >> 3, q = q2 & 7;
        int w2 = 64 + (q >> 2), sl = q & 3;
        *(int4*)(xs[bu] + ((y * 66 + w2) * 64 + sl * 16)) = int4{0, 0, 0, 0};
    }
    {
        f32x8 s0 = issueRow(d, 0), s1 = issueRow(d, 1), s2 = issueRow(d, 2);
        writeRow(xs[0], 0, s0); s0 = issueRow(d, 3);
        writeRow(xs[0], 1, s1); s1 = issueRow(d, 4);
        writeRow(xs[0], 2, s2); s2 = issueRow(d, 5);
        writeRow(xs[0], 3, s0); writeRow(xs[0], 4, s1); writeRow(xs[0], 5, s2);
    }
    int4 af[2][4];
    loadA(0, af[0]);
    __syncthreads();

    f32x4 acc[4][4];
#pragma unroll
    for (int mt = 0; mt < 4; ++mt)
#pragma unroll
        for (int nt = 0; nt < 4; ++nt)
            acc[mt][nt] = f32x4{0.f, 0.f, 0.f, 0.f};

    int4 bfr[2][4];

#pragma unroll
    for (int kz = 0; kz < 3; ++kz) {
        char* cur = xs[kz & 1];
        char* nxt = xs[(kz + 1) & 1];
        f32x8 s0, s1, s2;
        readB(cur, 0, 0, bfr[0]);
#pragma unroll
        for (int t = 0; t < 9; ++t) {
            const int T = kz * 9 + t;
            if (T < 26) loadA(T + 1, af[(T + 1) & 1]);
            if (t < 8)  readB(cur, (t + 1) / 3, (t + 1) % 3, bfr[(t + 1) & 1]);
            if (kz < 2) {
                if (t == 3) writeRow(nxt, 0, s0);
                if (t == 4) writeRow(nxt, 1, s1);
                if (t == 5) writeRow(nxt, 2, s2);
                if (t == 6) writeRow(nxt, 3, s0);
                if (t == 7) writeRow(nxt, 4, s1);
                if (t == 8) writeRow(nxt, 5, s2);
                if (t == 0) s0 = issueRow(d + kz + 1, 0);
                if (t == 1) s1 = issueRow(d + kz + 1, 1);
                if (t == 2) s2 = issueRow(d + kz + 1, 2);
                if (t == 3) s0 = issueRow(d + kz + 1, 3);
                if (t == 4) s1 = issueRow(d + kz + 1, 4);
                if (t == 5) s2 = issueRow(d + kz + 1, 5);
            }
#pragma unroll
            for (int mt = 0; mt < 4; ++mt)
#pragma unroll
                for (int nt = 0; nt < 4; ++nt)
                    acc[mt][nt] = __builtin_amdgcn_mfma_f32_16x16x32_bf16(
                        __builtin_bit_cast(bf16x8, af[T & 1][mt]),
                        __builtin_bit_cast(bf16x8, bfr[t & 1][nt]),
                        acc[mt][nt], 0, 0, 0);
        }
        if (kz < 2) __syncthreads();
    }

    const int h = h0 + row;
    if (h < DOUT) {
#pragma unroll
        for (int mt = 0; mt < 4; ++mt) {
#pragma unroll
            for (int r = 0; r < 4; ++r) {
                int oc = mt * 16 + whi * 4 + r;
                size_t ob = ((((size_t)b * OCH + oc) * DOUT + d) * DOUT + h) * DOUT;
#pragma unroll
                for (int nt = 0; nt < 4; ++nt) {
                    int ww = nt * 16 + wlo;
                    if (ww < DOUT) out[ob + ww] = acc[mt][nt][r];
                }
            }
        }
    }
}

extern "C" void kernel_launch(void* const* d_in, const int* in_sizes, int n_in,
                              void* d_out, int out_size, void* d_ws, size_t ws_size,
                              hipStream_t stream) {
    const float* x = (const float*)d_in[0];
    const float* W = (const float*)d_in[1];
    float* out = (float*)d_out;

    const dim3 grid(2 * DOUT * 16);                  // 1984 = 8 XCDs * 248
    const size_t wre_elems = (size_t)27 * OCH * ICH;             // 55,296 ushort
    const size_t xp_elems  = (size_t)2 * DIN * DIN * DIN * ICH;  // 16,777,216 ushort
    const size_t need = (wre_elems + xp_elems) * 2 + 256;

    if (ws_size >= need) {
        unsigned short* Wre3 = (unsigned short*)d_ws;
        unsigned short* xp   = Wre3 + wre_elems;
        prep_w<<<216, 256, 0, stream>>>(W, Wre3);
        prep_x<<<2048, 256, 0, stream>>>(x, xp);
        conv3d_mfma_pk<<<grid, 256, 0, stream>>>(Wre3, xp, out);
    } else {
        conv3d_mfma_fb<<<grid, 256, 0, stream>>>(x, W, out);
    }
}

// Round 12
// 88.183 us; speedup vs baseline: 1.2548x; 1.2548x over previous
//
#include <hip/hip_runtime.h>
#include <hip/hip_bf16.h>

#define DIN 64
#define DOUT 62
#define ICH 32
#define OCH 64

typedef __bf16 bf16x8 __attribute__((ext_vector_type(8)));
typedef float f32x4 __attribute__((ext_vector_type(4)));
typedef float f32x8 __attribute__((ext_vector_type(8)));
typedef float f32x16 __attribute__((ext_vector_type(16)));

#define AS1U(p) ((const __attribute__((address_space(1))) unsigned int*)(p))
#define AS3U(p) ((__attribute__((address_space(3))) unsigned int*)(p))

// ---------- prep: W -> Wre3 in 32x32x16-fragment-linear order ----------
// Wre3[(((tap*2+mt)*2+kh)*64+lane)*8+j] = bf16( W[oc=mt*32+(lane&31)][ic=kh*16+(lane>>5)*8+j][tap] )
// Per tap: 256 int4.  loadA(tap) = 4 coalesced dwordx4 (1KB segments).
__global__ void prep_w(const float* __restrict__ W, unsigned short* __restrict__ Wre3) {
    int idx = blockIdx.x * 256 + threadIdx.x;        // 27*2*2*64*8 = 55296
    if (idx >= 27 * OCH * ICH) return;
    int j    = idx & 7;
    int lane = (idx >> 3) & 63;
    int kh   = (idx >> 9) & 1;
    int mt   = (idx >> 10) & 1;
    int tap  = idx >> 11;
    int oc   = mt * 32 + (lane & 31);
    int ic   = kh * 16 + (lane >> 5) * 8 + j;
    float v  = W[((size_t)oc * ICH + ic) * 27 + tap];
    Wre3[idx] = __builtin_bit_cast(unsigned short, (__bf16)v);
}

// ---------- prep: x f32 -> xp bf16, SLICE-MAJOR: xp[b][z][y][s(4)][w(64)][8ic] ----------
// slice s holds ic = 8s..8s+7.  ds_read for fixed (kh) is then 2 contiguous 512B runs
// (lanes 0-31 -> slice 2kh, lanes 32-63 -> slice 2kh+1): bank-conflict-free, no XOR.
__global__ void prep_x(const float* __restrict__ x, unsigned short* __restrict__ xp) {
    int idx = blockIdx.x * 256 + threadIdx.x;        // 2*64*64*4*64 = 2,097,152
    int w = idx & 63;
    int s = (idx >> 6) & 3;
    int y = (idx >> 8) & 63;
    int z = (idx >> 14) & 63;
    int b = idx >> 20;
    const float* xb = x + ((size_t)(b * ICH + s * 8)) * 262144 + (size_t)z * 4096 + y * 64 + w;
    bf16x8 pk;
#pragma unroll
    for (int j = 0; j < 8; ++j)
        pk[j] = (__bf16)xb[(size_t)j * 262144];
    ((int4*)xp)[idx] = __builtin_bit_cast(int4, pk);
}

// ---------- main: implicit GEMM, 32x32x16 MFMA, per-tap interleaved staging ----------
// block tile: (b, d, 4 h-rows) x 64 oc x 64 w.  wave = one h row; per wave 2x2 32x32 tiles.
// LDS plane 24KB: [y(6)][s(4)][w(64)][16B], copied linearly from xp.
__global__ __launch_bounds__(256, 3) void conv3d_mfma_pk(
    const unsigned short* __restrict__ Wre3,
    const unsigned short* __restrict__ xp,
    float* __restrict__ out)
{
    __shared__ char xs[2 * 24576 + 256];             // 2 plane bufs + guard

    const int tid  = threadIdx.x;
    const int lane = tid & 63;
    const int wave = tid >> 6;

    // bijective XCD-aware swizzle (nwg = 1984 = 8*248 exactly)
    const int orig = blockIdx.x;
    const int lid  = (orig & 7) * 248 + (orig >> 3);
    const int ht = lid & 15;
    const int rr = lid >> 4;
    const int d  = rr % DOUT;
    const int b  = rr / DOUT;
    const int h0 = ht * 4;

    const int l31 = lane & 31;                       // w-in-tile / oc-in-tile
    const int lhi = lane >> 5;                       // k-subgroup (8 ic) within k-half
    const int row = wave;                            // h row

    // one 1KB chunk (c = y*4+s) of a plane: one global_load_lds_dwordx4, linear dest
    auto stage_chunk = [&](char* buf, int z, int i) {
        int c  = wave * 6 + i;                       // 0..23
        int yl = c >> 2;                             // y row 0..5
        int sl = c & 3;                              // ic-slice
        int srow = h0 + yl; if (srow > 63) srow = 63;   // clamped rows feed only discarded h
        const unsigned short* src =
            xp + ((((size_t)(b * DIN + z) * DIN + srow) * 4 + sl) * 64) * 8 + lane * 8;
        __builtin_amdgcn_global_load_lds(AS1U(src), AS3U(buf + c * 1024), 16, 0, 0);
    };
    // A: af[q], q = mt*2+kh — 4 coalesced dwordx4 per tap (tap stride = 256 int4)
    auto loadA = [&](int tap, int4* af) {
        const int4* wp = (const int4*)Wre3 + (size_t)tap * 256 + lane;
#pragma unroll
        for (int q = 0; q < 4; ++q)
            af[q] = wp[q * 64];
    };
    // B: dst[kh*2+nt] — 4 x ds_read_b128, each 2 contiguous 512B runs (conflict-free)
    auto readB = [&](const char* buf, int ky, int kx, int4* dst) {
#pragma unroll
        for (int kh = 0; kh < 2; ++kh) {
            const int g = kh * 2 + lhi;              // ic-slice for this lane
#pragma unroll
            for (int nt = 0; nt < 2; ++nt) {
                int wb = nt * 32 + l31 + kx;
                if (wb > 63) wb = 63;                // cols 62/63 only (discarded outputs)
                dst[kh * 2 + nt] = *(const int4*)(buf + (((row + ky) * 4 + g) * 64 + wb) * 16);
            }
        }
    };

    char* bufA = xs;
    char* bufB = xs + 24576;

#pragma unroll
    for (int i = 0; i < 6; ++i) stage_chunk(bufA, d, i);   // plane kz=0 (burst, once)
    int4 af[2][4];
    loadA(0, af[0]);

    f32x16 acc[2][2];
#pragma unroll
    for (int mt = 0; mt < 2; ++mt)
#pragma unroll
        for (int nt = 0; nt < 2; ++nt)
#pragma unroll
            for (int r = 0; r < 16; ++r) acc[mt][nt][r] = 0.f;

    __syncthreads();                                 // plane 0 ready

    int4 bfr[2][4];

#pragma unroll                                        // kz static -> all indices compile-time
    for (int kz = 0; kz < 3; ++kz) {
        char* cur = (kz & 1) ? bufB : bufA;
        char* nxt = (kz & 1) ? bufA : bufB;
        readB(cur, 0, 0, bfr[0]);                    // per-segment B prologue

#pragma unroll
        for (int t = 0; t < 9; ++t) {
            const int T = kz * 9 + t;
            if (T < 26) loadA(T + 1, af[(T + 1) & 1]);                        // A: 1-deep
            if (t < 8)  readB(cur, (t + 1) / 3, (t + 1) % 3, bfr[(t + 1) & 1]); // B: 1-deep
            if (kz < 2 && t < 6) stage_chunk(nxt, d + kz + 1, t);   // after loadA (vmcnt order)

            __builtin_amdgcn_s_setprio(1);
#pragma unroll
            for (int mt = 0; mt < 2; ++mt)
#pragma unroll
                for (int nt = 0; nt < 2; ++nt) {
                    acc[mt][nt] = __builtin_amdgcn_mfma_f32_32x32x16_bf16(
                        __builtin_bit_cast(bf16x8, af[T & 1][mt * 2 + 0]),
                        __builtin_bit_cast(bf16x8, bfr[t & 1][0 * 2 + nt]),
                        acc[mt][nt], 0, 0, 0);
                    acc[mt][nt] = __builtin_amdgcn_mfma_f32_32x32x16_bf16(
                        __builtin_bit_cast(bf16x8, af[T & 1][mt * 2 + 1]),
                        __builtin_bit_cast(bf16x8, bfr[t & 1][1 * 2 + nt]),
                        acc[mt][nt], 0, 0, 0);
                }
            __builtin_amdgcn_s_setprio(0);
        }
        if (kz < 2) __syncthreads();                 // next plane landed
    }

    // ---- store: D col=lane&31 -> w, row=(r&3)+8*(r>>2)+4*(lane>>5) -> oc ----
    const int h = h0 + row;
    if (h < DOUT) {
#pragma unroll
        for (int mt = 0; mt < 2; ++mt) {
#pragma unroll
            for (int r = 0; r < 16; ++r) {
                int oc = mt * 32 + (r & 3) + 8 * (r >> 2) + 4 * lhi;
                size_t ob = ((((size_t)b * OCH + oc) * DOUT + d) * DOUT + h) * DOUT;
#pragma unroll
                for (int nt = 0; nt < 2; ++nt) {
                    int ww = nt * 32 + l31;
                    if (ww < DOUT) out[ob + ww] = acc[mt][nt][r];
                }
            }
        }
    }
}

// ---------- fallback (ws too small): reg-staged 16x16 kernel, f32 W direct ----------
__global__ __launch_bounds__(256, 3) void conv3d_mfma_fb(
    const float* __restrict__ x, const float* __restrict__ W,
    float* __restrict__ out)
{
    __shared__ char xs[2][6 * 66 * 64];

    const int tid  = threadIdx.x;
    const int lane = tid & 63;
    const int wave = tid >> 6;

    const int orig = blockIdx.x;
    const int lid  = (orig & 7) * 248 + (orig >> 3);
    const int ht = lid & 15;
    const int rr = lid >> 4;
    const int d  = rr % DOUT;
    const int b  = rr / DOUT;
    const int h0 = ht * 4;

    const int wlo = lane & 15;
    const int whi = lane >> 4;
    const int row = wave;

    const int icg  = wave;
    const int w    = lane;
    const int slot = icg ^ ((w >> 1) & 3);

    auto issueRow = [&](int z, int y) -> f32x8 {
        int gy = h0 + y; if (gy > 63) gy = 63;
        const float* xp2 = x + (((size_t)(b * ICH + icg * 8) * DIN + z) * DIN + gy) * DIN + w;
        f32x8 s;
#pragma unroll
        for (int j = 0; j < 8; ++j) s[j] = xp2[(size_t)j * DIN * DIN * DIN];
        return s;
    };
    auto writeRow = [&](char* buf, int y, f32x8 s) {
        bf16x8 pk;
#pragma unroll
        for (int j = 0; j < 8; ++j) pk[j] = (__bf16)s[j];
        *(int4*)(buf + ((y * 66 + w) * 64 + slot * 16)) = __builtin_bit_cast(int4, pk);
    };
    auto loadA = [&](int tap, int4* af) {
#pragma unroll
        for (int mt = 0; mt < 4; ++mt) {
            const float* wp = W + ((size_t)(mt * 16 + wlo) * ICH + whi * 8) * 27 + tap;
            bf16x8 t;
#pragma unroll
            for (int j = 0; j < 8; ++j) t[j] = (__bf16)wp[j * 27];
            af[mt] = __builtin_bit_cast(int4, t);
        }
    };
    auto readB = [&](const char* buf, int ky, int kx, int4* dst) {
#pragma unroll
        for (int nt = 0; nt < 4; ++nt) {
            int wb = nt * 16 + wlo + kx;
            int sl = whi ^ ((wb >> 1) & 3);
            dst[nt] = *(const int4*)(buf + (((row + ky) * 66 + wb) * 64 + sl * 16));
        }
    };

    if (tid < 96) {
        int bu = tid / 48, q2 = tid % 48;
        int y = q2 >> 3, q = q2 & 7;
        int w2 = 64 + (q >> 2), sl = q & 3;
        *(int4*)(xs[bu] + ((y * 66 + w2) * 64 + sl * 16)) = int4{0, 0, 0, 0};
    }
    {
        f32x8 s0 = issueRow(d, 0), s1 = issueRow(d, 1), s2 = issueRow(d, 2);
        writeRow(xs[0], 0, s0); s0 = issueRow(d, 3);
        writeRow(xs[0], 1, s1); s1 = issueRow(d, 4);
        writeRow(xs[0], 2, s2); s2 = issueRow(d, 5);
        writeRow(xs[0], 3, s0); writeRow(xs[0], 4, s1); writeRow(xs[0], 5, s2);
    }
    int4 af[2][4];
    loadA(0, af[0]);
    __syncthreads();

    f32x4 acc[4][4];
#pragma unroll
    for (int mt = 0; mt < 4; ++mt)
#pragma unroll
        for (int nt = 0; nt < 4; ++nt)
            acc[mt][nt] = f32x4{0.f, 0.f, 0.f, 0.f};

    int4 bfr[2][4];

#pragma unroll
    for (int kz = 0; kz < 3; ++kz) {
        char* cur = xs[kz & 1];
        char* nxt = xs[(kz + 1) & 1];
        f32x8 s0, s1, s2;
        readB(cur, 0, 0, bfr[0]);
#pragma unroll
        for (int t = 0; t < 9; ++t) {
            const int T = kz * 9 + t;
            if (T < 26) loadA(T + 1, af[(T + 1) & 1]);
            if (t < 8)  readB(cur, (t + 1) / 3, (t + 1) % 3, bfr[(t + 1) & 1]);
            if (kz < 2) {
                if (t == 3) writeRow(nxt, 0, s0);
                if (t == 4) writeRow(nxt, 1, s1);
                if (t == 5) writeRow(nxt, 2, s2);
                if (t == 6) writeRow(nxt, 3, s0);
                if (t == 7) writeRow(nxt, 4, s1);
                if (t == 8) writeRow(nxt, 5, s2);
                if (t == 0) s0 = issueRow(d + kz + 1, 0);
                if (t == 1) s1 = issueRow(d + kz + 1, 1);
                if (t == 2) s2 = issueRow(d + kz + 1, 2);
                if (t == 3) s0 = issueRow(d + kz + 1, 3);
                if (t == 4) s1 = issueRow(d + kz + 1, 4);
                if (t == 5) s2 = issueRow(d + kz + 1, 5);
            }
#pragma unroll
            for (int mt = 0; mt < 4; ++mt)
#pragma unroll
                for (int nt = 0; nt < 4; ++nt)
                    acc[mt][nt] = __builtin_amdgcn_mfma_f32_16x16x32_bf16(
                        __builtin_bit_cast(bf16x8, af[T & 1][mt]),
                        __builtin_bit_cast(bf16x8, bfr[t & 1][nt]),
                        acc[mt][nt], 0, 0, 0);
        }
        if (kz < 2) __syncthreads();
    }

    const int h = h0 + row;
    if (h < DOUT) {
#pragma unroll
        for (int mt = 0; mt < 4; ++mt) {
#pragma unroll
            for (int r = 0; r < 4; ++r) {
                int oc = mt * 16 + whi * 4 + r;
                size_t ob = ((((size_t)b * OCH + oc) * DOUT + d) * DOUT + h) * DOUT;
#pragma unroll
                for (int nt = 0; nt < 4; ++nt) {
                    int ww = nt * 16 + wlo;
                    if (ww < DOUT) out[ob + ww] = acc[mt][nt][r];
                }
            }
        }
    }
}

extern "C" void kernel_launch(void* const* d_in, const int* in_sizes, int n_in,
                              void* d_out, int out_size, void* d_ws, size_t ws_size,
                              hipStream_t stream) {
    const float* x = (const float*)d_in[0];
    const float* W = (const float*)d_in[1];
    float* out = (float*)d_out;

    const dim3 grid(2 * DOUT * 16);                  // 1984 = 8 XCDs * 248
    const size_t wre_elems = (size_t)27 * OCH * ICH;             // 55,296 ushort
    const size_t xp_elems  = (size_t)2 * DIN * DIN * DIN * ICH;  // 16,777,216 ushort
    const size_t need = (wre_elems + xp_elems) * 2 + 256;

    if (ws_size >= need) {
        unsigned short* Wre3 = (unsigned short*)d_ws;
        unsigned short* xp   = Wre3 + wre_elems;
        prep_w<<<216, 256, 0, stream>>>(W, Wre3);
        prep_x<<<8192, 256, 0, stream>>>(x, xp);
        conv3d_mfma_pk<<<grid, 256, 0, stream>>>(Wre3, xp, out);
    } else {
        conv3d_mfma_fb<<<grid, 256, 0, stream>>>(x, W, out);
    }
}